// Round 1
// 2069.254 us; speedup vs baseline: 1.1371x; 1.1371x over previous
//
#include <hip/hip_runtime.h>

// ---------------------------------------------------------------------------
// 6-layer Transformer encoder, MI355X gfx950.
// fp16 MFMA GEMMs + flash attention, fp32 residual/LN chain.
// R5: attention rewritten around mfma_f32_32x32x16_f16 with SWAPPED QK^T
//     (S^T = K·Q^T) so softmax state is lane-local per q-column:
//     - in-register max/sum (one shfl_xor(32) each, was 32 shfls/tile)
//     - P packed via v_cvt_pkrtz + 2-dword partner exchange (no Ps LDS,
//       kills the 7.08M bank-conflict cycles of scalar f16 P writes)
//     - PV computes O^T = V^T · P^T so rescale/finalize stay lane-local
//     - exp2-folded softmax scale (0.125*log2e in one fma)
//     - waves own 32 q rows; blocks 128 q rows (grid 96x8 = 3 blocks/CU)
// ---------------------------------------------------------------------------

typedef _Float16 f16;
typedef _Float16 half8 __attribute__((ext_vector_type(8)));
typedef float f32x4 __attribute__((ext_vector_type(4)));
typedef float f32x16 __attribute__((ext_vector_type(16)));

constexpr int Bn = 8, Sn = 1024, Dn = 768, Hn = 12, HDn = 64, DFn = 3072, Ln = 6;
constexpr int BS = Bn * Sn;  // 8192 rows

__device__ __forceinline__ void glds16(const f16* g, f16* l) {
  __builtin_amdgcn_global_load_lds(
      (const __attribute__((address_space(1))) unsigned int*)g,
      (__attribute__((address_space(3))) unsigned int*)l, 16, 0, 0);
}

__device__ __forceinline__ float ex2(float x) {
#if __has_builtin(__builtin_amdgcn_exp2f)
  return __builtin_amdgcn_exp2f(x);
#else
  return exp2f(x);
#endif
}

// ---------------------------------------------------------------------------
// Weight prep: pack [Wq;Wk;Wv] per layer into (2304 x 768) fp16 + packed bias
// ---------------------------------------------------------------------------
__global__ __launch_bounds__(256) void pack_qkv(
    const float* __restrict__ Wq, const float* __restrict__ Wk, const float* __restrict__ Wv,
    const float* __restrict__ bq, const float* __restrict__ bk, const float* __restrict__ bv,
    f16* __restrict__ Wo, float* __restrict__ bo) {
  const long per = (long)Dn * Dn;  // 589824
  long i = (long)blockIdx.x * 256 + threadIdx.x;
  const long totalW = (long)Ln * 3 * per;
  if (i < totalW) {
    int l = (int)(i / (3 * per));
    long rem = i - (long)l * 3 * per;
    int which = (int)(rem / per);
    long e = rem - (long)which * per;
    const float* s = (which == 0) ? Wq : ((which == 1) ? Wk : Wv);
    Wo[i] = (f16)(s[(long)l * per + e]);
  }
  if (i < (long)Ln * 3 * Dn) {  // 13824 bias elems
    int l = (int)(i / (3 * Dn));
    int rem = (int)(i % (3 * Dn));
    int which = rem / Dn, c = rem % Dn;
    const float* s = (which == 0) ? bq : ((which == 1) ? bk : bv);
    bo[i] = s[l * Dn + c];
  }
}

__global__ __launch_bounds__(256) void f32_to_f16_k(
    const float* __restrict__ src, f16* __restrict__ dst, long n) {
  long i = ((long)blockIdx.x * 256 + threadIdx.x) * 4;
  if (i < n) {
    float4 v = *(const float4*)&src[i];
    dst[i + 0] = (f16)v.x;
    dst[i + 1] = (f16)v.y;
    dst[i + 2] = (f16)v.z;
    dst[i + 3] = (f16)v.w;
  }
}

// ---------------------------------------------------------------------------
// Embedding gather + positional encoding -> fp32 X and fp16 Xh
// ---------------------------------------------------------------------------
__global__ __launch_bounds__(256) void embed_k(
    const int* __restrict__ ids, const float* __restrict__ emb, const float* __restrict__ pe,
    float* __restrict__ Xf, f16* __restrict__ Xh) {
  const int row = blockIdx.x;           // 0..8191
  const int s = row & (Sn - 1);
  const int id = ids[row];
  const size_t eb = (size_t)id * Dn, pb = (size_t)s * Dn, ob = (size_t)row * Dn;
  for (int c = threadIdx.x; c < Dn; c += 256) {
    float v = emb[eb + c] + pe[pb + c];
    Xf[ob + c] = v;
    Xh[ob + c] = (f16)v;
  }
}

// ---------------------------------------------------------------------------
// bt-GEMM: C(M,N) = A(MxK) @ B(NxK)^T + bias, 128x128x32 tile, 4 waves.
// MODE 1: relu + fp16 out.  MODE 2: fp32 out.  MODE 3: fp16 QKV split.
// ---------------------------------------------------------------------------
template <int MODE>
__global__ __launch_bounds__(256) void gemm_bt(
    const f16* __restrict__ A, const f16* __restrict__ Bw, const float* __restrict__ bias,
    float* __restrict__ outF, f16* __restrict__ o0, f16* __restrict__ o1, f16* __restrict__ o2,
    int M, int N, int K) {
  const int m0 = blockIdx.x * 128;
  const int n0 = blockIdx.y * 128;
  const int tid = threadIdx.x;
  const int lane = tid & 63, wave = tid >> 6;
  const int wm = wave & 1, wn = wave >> 1;
  const int l15 = lane & 15, l4 = lane >> 4;

  __shared__ __align__(16) f16 As[128 * 32];  // unpadded: required by glds
  __shared__ __align__(16) f16 Bs[128 * 32];

  const f32x4 z4 = {0.f, 0.f, 0.f, 0.f};
  f32x4 acc[4][4];
#pragma unroll
  for (int i = 0; i < 4; i++)
#pragma unroll
    for (int j = 0; j < 4; j++) acc[i][j] = z4;

  const int sRow = wave * 32 + (lane >> 2);
  const int sCol = (lane & 3) * 8;
  const f16* gA = A + (size_t)(m0 + sRow) * K + sCol;
  const f16* gB = Bw + (size_t)(n0 + sRow) * K + sCol;
  f16* lA0 = &As[(wave * 32) * 32];
  f16* lA1 = &As[(wave * 32 + 16) * 32];
  f16* lB0 = &Bs[(wave * 32) * 32];
  f16* lB1 = &Bs[(wave * 32 + 16) * 32];
  const size_t rowStep = (size_t)16 * K;

  const int kr = 8 * l4;
  for (int k0 = 0; k0 < K; k0 += 32) {
    glds16(gA + k0, lA0);
    glds16(gA + k0 + rowStep, lA1);
    glds16(gB + k0, lB0);
    glds16(gB + k0 + rowStep, lB1);
    __syncthreads();
    half8 af[4], bfr[4];
#pragma unroll
    for (int i = 0; i < 4; i++) af[i] = *(const half8*)&As[(wm * 64 + i * 16 + l15) * 32 + kr];
#pragma unroll
    for (int j = 0; j < 4; j++) bfr[j] = *(const half8*)&Bs[(wn * 64 + j * 16 + l15) * 32 + kr];
#pragma unroll
    for (int i = 0; i < 4; i++)
#pragma unroll
      for (int j = 0; j < 4; j++)
        acc[i][j] = __builtin_amdgcn_mfma_f32_16x16x32_f16(af[i], bfr[j], acc[i][j], 0, 0, 0);
    __syncthreads();
  }

  const int colb = n0 + wn * 64;
  const int rowb = m0 + wm * 64;
#pragma unroll
  for (int j = 0; j < 4; j++) {
    const int col = colb + j * 16 + l15;
    const float bb = bias[col];
#pragma unroll
    for (int i = 0; i < 4; i++) {
      const int rb = rowb + i * 16 + l4 * 4;
#pragma unroll
      for (int r = 0; r < 4; r++) {
        float v = acc[i][j][r] + bb;
        const int row = rb + r;
        if (MODE == 1) v = fmaxf(v, 0.f);
        if (MODE == 2) {
          outF[(size_t)row * N + col] = v;
        } else if (MODE == 3) {
          const int sel = col / 768;          // block-uniform (768 % 128 == 0)
          const int cl = col - sel * 768;
          f16* op = (sel == 0) ? o0 : ((sel == 1) ? o1 : o2);
          op[(size_t)row * 768 + cl] = (f16)v;
        } else {
          o0[(size_t)row * N + col] = (f16)v;
        }
      }
    }
  }
}

// ---------------------------------------------------------------------------
// Flash attention v2: one block = (b,h) x 128 q-rows; 4 waves x 32 rows each.
// 32x32x16 MFMA, swapped QK^T (S^T = K·Q^T): lane owns q-column (q = lane&31),
// partner lane (^32) holds complementary 32 kpos. Softmax fully in-register.
// PV computes O^T = V^T · P^T so per-q state never crosses lanes.
//
// Layouts (all verified against m74/m101 C-layout: col=lane&31,
// row=(reg&3)+8*(reg>>2)+4*(lane>>5); A/B frag: idx=lane&31, k=8*(lane>>5)+j):
//   s0/s1[reg]  = S^T[kpos = g*32 + (reg&3)+8*(reg>>2)+4*hi][q = l31]
//   pA[g][t]    = pkrtz(p[4t+0],p[4t+1])  -> kpos' = 8t+4*hi+{0,1} in group g
//   PV chunk c (kpos 16c..16c+15): B-frag slots =
//     [hiS0.dA[2(c&1)+hi], hiS0.dB[..], hiS1.dA[..], hiS1.dB[..]]
//   own index = tt+hi, send index = tt+1-hi, exchange via shfl_xor(32).
// ---------------------------------------------------------------------------
__global__ __launch_bounds__(256, 3) void attn_k(
    const f16* __restrict__ Qg, const f16* __restrict__ Kg, const f16* __restrict__ Vg,
    float* __restrict__ O) {
  const int bh = blockIdx.x;            // 0..95
  const int q0 = blockIdx.y * 128;
  const int b = bh / Hn, h = bh - b * Hn;
  const size_t base = (size_t)b * (Sn * Dn) + (size_t)h * (Sn * HDn);
  const f16* Qh = Qg + base;
  const f16* Kh = Kg + base;
  const f16* Vh = Vg + base;

  const int tid = threadIdx.x, lane = tid & 63, wave = tid >> 6;
  const int l31 = lane & 31;
  const int hi = lane >> 5;             // 0/1: which half of the 64-kpos tile

  __shared__ __align__(16) f16 Ks[64 * 72];   // (kpos, hd), padded stride 72
  __shared__ __align__(16) f16 Vt[64 * 72];   // (hd, kpos), padded stride 72

  const int qrow = q0 + wave * 32 + l31;
  half8 qf[4];
#pragma unroll
  for (int m = 0; m < 4; m++)
    qf[m] = *(const half8*)&Qh[(size_t)qrow * HDn + 16 * m + 8 * hi];

  f32x16 Oacc0, Oacc1;
#pragma unroll
  for (int i = 0; i < 16; i++) { Oacc0[i] = 0.f; Oacc1[i] = 0.f; }
  float mrow = -1e30f, lrow = 0.f;
  const float csc = 0.18033688011112042f;  // 0.125 * log2(e)

  for (int kt = 0; kt < Sn / 64; ++kt) {
    // stage K tile 64x64 (row-major, conflict-free b128 writes)
#pragma unroll
    for (int cc = 0; cc < 2; cc++) {
      const int c = tid + cc * 256;
      const int row = c >> 3, col = (c & 7) * 8;
      *(int4*)&Ks[row * 72 + col] = *(const int4*)&Kh[(size_t)(kt * 64 + row) * HDn + col];
    }
    // stage V transposed: 8 coalesced col-gathers -> one aligned b128 write
#pragma unroll
    for (int ee = 0; ee < 2; ee++) {
      const int e = tid + ee * 256;
      const int hd = e & 63, kpo = e >> 6;
      f16 tmp[8];
#pragma unroll
      for (int j = 0; j < 8; j++)
        tmp[j] = Vh[(size_t)(kt * 64 + kpo * 8 + j) * HDn + hd];
      *(int4*)&Vt[hd * 72 + kpo * 8] = *(const int4*)tmp;
    }
    __syncthreads();

    // QK^T swapped: S^T (64 kpos x 32 q) as two 32x32 tiles, contraction hd=64
    f32x16 s0, s1;
#pragma unroll
    for (int i = 0; i < 16; i++) { s0[i] = 0.f; s1[i] = 0.f; }
#pragma unroll
    for (int m = 0; m < 4; m++) {
      half8 k0 = *(const half8*)&Ks[l31 * 72 + 16 * m + 8 * hi];
      half8 k1 = *(const half8*)&Ks[(32 + l31) * 72 + 16 * m + 8 * hi];
      s0 = __builtin_amdgcn_mfma_f32_32x32x16_f16(k0, qf[m], s0, 0, 0, 0);
      s1 = __builtin_amdgcn_mfma_f32_32x32x16_f16(k1, qf[m], s1, 0, 0, 0);
    }

    // column max over 64 kpos: in-register tree + one partner exchange
    float t8[8];
#pragma unroll
    for (int i = 0; i < 8; i++)
      t8[i] = fmaxf(fmaxf(s0[i], s0[i + 8]), fmaxf(s1[i], s1[i + 8]));
#pragma unroll
    for (int i = 0; i < 4; i++) t8[i] = fmaxf(t8[i], t8[i + 4]);
    float mx = fmaxf(fmaxf(t8[0], t8[1]), fmaxf(t8[2], t8[3]));
    mx = fmaxf(mx, __shfl_xor(mx, 32));
    const float M = fmaxf(mrow, mx * csc);
    const float alpha = ex2(mrow - M);

    // p = exp2(s*csc - M), in place
#pragma unroll
    for (int i = 0; i < 16; i++) {
      s0[i] = ex2(fmaf(s0[i], csc, -M));
      s1[i] = ex2(fmaf(s1[i], csc, -M));
    }
    float r0 = 0.f, r1 = 0.f, r2 = 0.f, r3 = 0.f;
#pragma unroll
    for (int i = 0; i < 16; i += 4) {
      r0 += s0[i]; r1 += s0[i + 1]; r2 += s0[i + 2]; r3 += s0[i + 3];
      r0 += s1[i]; r1 += s1[i + 1]; r2 += s1[i + 2]; r3 += s1[i + 3];
    }
    float rsum = (r0 + r1) + (r2 + r3);
    rsum += __shfl_xor(rsum, 32);
    lrow = lrow * alpha + rsum;
    mrow = M;
#pragma unroll
    for (int i = 0; i < 16; i++) { Oacc0[i] *= alpha; Oacc1[i] *= alpha; }

    // pack P (f32 -> packed f16 pairs)
    unsigned pA[2][4], pB[2][4];
#pragma unroll
    for (int t = 0; t < 4; t++) {
      pA[0][t] = __builtin_bit_cast(unsigned, __builtin_amdgcn_cvt_pkrtz(s0[4 * t + 0], s0[4 * t + 1]));
      pB[0][t] = __builtin_bit_cast(unsigned, __builtin_amdgcn_cvt_pkrtz(s0[4 * t + 2], s0[4 * t + 3]));
      pA[1][t] = __builtin_bit_cast(unsigned, __builtin_amdgcn_cvt_pkrtz(s1[4 * t + 0], s1[4 * t + 1]));
      pB[1][t] = __builtin_bit_cast(unsigned, __builtin_amdgcn_cvt_pkrtz(s1[4 * t + 2], s1[4 * t + 3]));
    }

    // PV: O^T (64 hd x 32 q) += V^T · P^T, 4 chunks of 16 kpos
#pragma unroll
    for (int c = 0; c < 4; c++) {
      const int g = c >> 1, tt = 2 * (c & 1);
      const unsigned ownA = hi ? pA[g][tt + 1] : pA[g][tt];
      const unsigned ownB = hi ? pB[g][tt + 1] : pB[g][tt];
      const unsigned sndA = hi ? pA[g][tt] : pA[g][tt + 1];
      const unsigned sndB = hi ? pB[g][tt] : pB[g][tt + 1];
      const unsigned rA = (unsigned)__shfl_xor((int)sndA, 32);
      const unsigned rB = (unsigned)__shfl_xor((int)sndB, 32);
      int4 w;
      w.x = (int)(hi ? rA : ownA);
      w.y = (int)(hi ? rB : ownB);
      w.z = (int)(hi ? ownA : rA);
      w.w = (int)(hi ? ownB : rB);
      const half8 pf = __builtin_bit_cast(half8, w);
      const half8 v0 = *(const half8*)&Vt[l31 * 72 + 16 * c + 8 * hi];
      const half8 v1 = *(const half8*)&Vt[(32 + l31) * 72 + 16 * c + 8 * hi];
      Oacc0 = __builtin_amdgcn_mfma_f32_32x32x16_f16(v0, pf, Oacc0, 0, 0, 0);
      Oacc1 = __builtin_amdgcn_mfma_f32_32x32x16_f16(v1, pf, Oacc1, 0, 0, 0);
    }
    __syncthreads();
  }

  // finalize: O[b][s=qrow][h*64 + hd], hd = ht*32 + 8t + 4*hi + e (contiguous 4)
  const float inv = 1.f / lrow;
  float* Orow = O + ((size_t)b * Sn + qrow) * Dn + h * HDn;
#pragma unroll
  for (int t = 0; t < 4; t++) {
    float4 o0, o1;
    o0.x = Oacc0[4 * t + 0] * inv; o0.y = Oacc0[4 * t + 1] * inv;
    o0.z = Oacc0[4 * t + 2] * inv; o0.w = Oacc0[4 * t + 3] * inv;
    o1.x = Oacc1[4 * t + 0] * inv; o1.y = Oacc1[4 * t + 1] * inv;
    o1.z = Oacc1[4 * t + 2] * inv; o1.w = Oacc1[4 * t + 3] * inv;
    *(float4*)&Orow[8 * t + 4 * hi] = o0;
    *(float4*)&Orow[32 + 8 * t + 4 * hi] = o1;
  }
}

// ---------------------------------------------------------------------------
// Residual add + LayerNorm over D=768, one block per row (256 thr x 3 elems).
// ---------------------------------------------------------------------------
__global__ __launch_bounds__(256) void add_ln(
    const float* __restrict__ Xi, const float* __restrict__ Hr,
    const float* __restrict__ g, const float* __restrict__ bt,
    float* __restrict__ Yf, f16* __restrict__ Yh) {
  const int row = blockIdx.x;
  const int tid = threadIdx.x;
  const size_t base = (size_t)row * Dn;
  float v0 = Xi[base + tid] + Hr[base + tid];
  float v1 = Xi[base + tid + 256] + Hr[base + tid + 256];
  float v2 = Xi[base + tid + 512] + Hr[base + tid + 512];

  __shared__ float red[8];
  float s = v0 + v1 + v2;
  for (int off = 32; off; off >>= 1) s += __shfl_down(s, off);
  const int wv = tid >> 6, ln = tid & 63;
  if (ln == 0) red[wv] = s;
  __syncthreads();
  if (tid == 0) red[4] = (red[0] + red[1] + red[2] + red[3]) * (1.f / Dn);
  __syncthreads();
  const float mu = red[4];
  const float d0 = v0 - mu, d1 = v1 - mu, d2 = v2 - mu;
  float vs = d0 * d0 + d1 * d1 + d2 * d2;
  for (int off = 32; off; off >>= 1) vs += __shfl_down(vs, off);
  if (ln == 0) red[wv] = vs;
  __syncthreads();
  if (tid == 0) red[5] = rsqrtf((red[0] + red[1] + red[2] + red[3]) * (1.f / Dn) + 1e-5f);
  __syncthreads();
  const float rs = red[5];
  float y0 = d0 * rs * g[tid] + bt[tid];
  float y1 = d1 * rs * g[tid + 256] + bt[tid + 256];
  float y2 = d2 * rs * g[tid + 512] + bt[tid + 512];
  Yf[base + tid] = y0;        Yh[base + tid] = (f16)y0;
  Yf[base + tid + 256] = y1;  Yh[base + tid + 256] = (f16)y1;
  Yf[base + tid + 512] = y2;  Yh[base + tid + 512] = (f16)y2;
}

// ---------------------------------------------------------------------------
extern "C" void kernel_launch(void* const* d_in, const int* in_sizes, int n_in,
                              void* d_out, int out_size, void* d_ws, size_t ws_size,
                              hipStream_t stream) {
  const int* ids  = (const int*)d_in[0];
  const float* emb = (const float*)d_in[1];
  const float* pe  = (const float*)d_in[2];
  const float* Wq  = (const float*)d_in[3];
  const float* bq  = (const float*)d_in[4];
  const float* Wk  = (const float*)d_in[5];
  const float* bk  = (const float*)d_in[6];
  const float* Wv  = (const float*)d_in[7];
  const float* bv  = (const float*)d_in[8];
  const float* W1  = (const float*)d_in[9];
  const float* b1  = (const float*)d_in[10];
  const float* W2  = (const float*)d_in[11];
  const float* b2  = (const float*)d_in[12];
  const float* g1  = (const float*)d_in[13];
  const float* be1 = (const float*)d_in[14];
  const float* g2  = (const float*)d_in[15];
  const float* be2 = (const float*)d_in[16];
  float* out = (float*)d_out;

  // workspace layout (~292 MB)
  char* w = (char*)d_ws;
  auto alloc = [&](size_t bytes) {
    char* p = w;
    w += (bytes + 255) & ~(size_t)255;
    return p;
  };
  f16* Wqkv  = (f16*)alloc((size_t)Ln * 3 * Dn * Dn * 2);
  float* bqkv = (float*)alloc((size_t)Ln * 3 * Dn * 4);
  f16* W1h   = (f16*)alloc((size_t)Ln * DFn * Dn * 2);
  f16* W2h   = (f16*)alloc((size_t)Ln * Dn * DFn * 2);
  float* Xf  = (float*)alloc((size_t)BS * Dn * 4);
  f16* Xh    = (f16*)alloc((size_t)BS * Dn * 2);
  f16* Qh    = (f16*)alloc((size_t)BS * Dn * 2);
  f16* Kh    = (f16*)alloc((size_t)BS * Dn * 2);
  f16* Vh    = (f16*)alloc((size_t)BS * Dn * 2);
  float* Of  = (float*)alloc((size_t)BS * Dn * 4);
  float* Y1f = (float*)alloc((size_t)BS * Dn * 4);
  f16* Y1h   = (f16*)alloc((size_t)BS * Dn * 2);
  f16* F1h   = (f16*)alloc((size_t)BS * DFn * 2);
  float* H2f = (float*)alloc((size_t)BS * Dn * 4);

  // weight conversion (every call; harness re-poisons ws)
  {
    const int gw = (Ln * 3 * Dn * Dn + 255) / 256;  // 41472 blocks
    pack_qkv<<<gw, 256, 0, stream>>>(Wq, Wk, Wv, bq, bk, bv, Wqkv, bqkv);
    const long n1 = (long)Ln * DFn * Dn;
    const int gc = (int)(n1 / 4 / 256);             // 13824
    f32_to_f16_k<<<gc, 256, 0, stream>>>(W1, W1h, n1);
    f32_to_f16_k<<<gc, 256, 0, stream>>>(W2, W2h, n1);
  }

  embed_k<<<BS, 256, 0, stream>>>(ids, emb, pe, Xf, Xh);

  for (int l = 0; l < Ln; ++l) {
    // QKV: (8192 x 2304) = Xh @ Wqkv^T, split-written to Qh/Kh/Vh
    gemm_bt<3><<<dim3(BS / 128, (3 * Dn) / 128), 256, 0, stream>>>(
        Xh, Wqkv + (size_t)l * 3 * Dn * Dn, bqkv + l * 3 * Dn,
        nullptr, Qh, Kh, Vh, BS, 3 * Dn, Dn);

    attn_k<<<dim3(Bn * Hn, Sn / 128), 256, 0, stream>>>(Qh, Kh, Vh, Of);

    add_ln<<<BS, 256, 0, stream>>>(Xf, Of, g1 + l * Dn, be1 + l * Dn, Y1f, Y1h);

    // FFN1: relu(Y1 @ W1^T + b1) -> fp16
    gemm_bt<1><<<dim3(BS / 128, DFn / 128), 256, 0, stream>>>(
        Y1h, W1h + (size_t)l * DFn * Dn, b1 + l * DFn,
        nullptr, F1h, nullptr, nullptr, BS, DFn, Dn);

    // FFN2: F1 @ W2^T + b2 -> fp32
    gemm_bt<2><<<dim3(BS / 128, Dn / 128), 256, 0, stream>>>(
        F1h, W2h + (size_t)l * Dn * DFn, b2 + l * Dn,
        H2f, nullptr, nullptr, nullptr, BS, Dn, DFn);

    float* dstF = (l == Ln - 1) ? out : Xf;
    add_ln<<<BS, 256, 0, stream>>>(Y1f, H2f, g2 + l * Dn, be2 + l * Dn, dstF, Xh);
  }
}

// Round 2
// 1926.566 us; speedup vs baseline: 1.2213x; 1.0741x over previous
//
#include <hip/hip_runtime.h>

// ---------------------------------------------------------------------------
// 6-layer Transformer encoder, MI355X gfx950.
// fp16 MFMA GEMMs + flash attention, fp32 residual/LN chain.
// R6: FFN2 (M=8192,N=768,K=3072) was grid-starved: 384 blocks = 1.5/CU ->
//     15.9% occupancy, 93 us. Split-K2 via blockIdx.z -> 768 blocks (3/CU),
//     fp32 partials (no bias) overlaid on dead Qh/Kh/Vh/Of region; partial
//     sum + bias fused into the following add_ln (add_ln_sk2).
//     Also vectorized pack_qkv / f32_to_f16 (float4 -> half4).
// R5: attention on mfma_32x32x16 with swapped QK^T, in-register softmax.
// ---------------------------------------------------------------------------

typedef _Float16 f16;
typedef _Float16 half4 __attribute__((ext_vector_type(4)));
typedef _Float16 half8 __attribute__((ext_vector_type(8)));
typedef float f32x4 __attribute__((ext_vector_type(4)));
typedef float f32x16 __attribute__((ext_vector_type(16)));

constexpr int Bn = 8, Sn = 1024, Dn = 768, Hn = 12, HDn = 64, DFn = 3072, Ln = 6;
constexpr int BS = Bn * Sn;  // 8192 rows

__device__ __forceinline__ void glds16(const f16* g, f16* l) {
  __builtin_amdgcn_global_load_lds(
      (const __attribute__((address_space(1))) unsigned int*)g,
      (__attribute__((address_space(3))) unsigned int*)l, 16, 0, 0);
}

__device__ __forceinline__ float ex2(float x) {
#if __has_builtin(__builtin_amdgcn_exp2f)
  return __builtin_amdgcn_exp2f(x);
#else
  return exp2f(x);
#endif
}

// ---------------------------------------------------------------------------
// Weight prep: pack [Wq;Wk;Wv] per layer into (2304 x 768) fp16 + packed bias
// (vectorized: 4 elems/thread; 'per' divisible by 4 so groups never straddle)
// ---------------------------------------------------------------------------
__global__ __launch_bounds__(256) void pack_qkv(
    const float* __restrict__ Wq, const float* __restrict__ Wk, const float* __restrict__ Wv,
    const float* __restrict__ bq, const float* __restrict__ bk, const float* __restrict__ bv,
    f16* __restrict__ Wo, float* __restrict__ bo) {
  const long per = (long)Dn * Dn;  // 589824
  const long t = (long)blockIdx.x * 256 + threadIdx.x;
  const long totalW4 = (long)Ln * 3 * per / 4;  // 2,654,208
  if (t < totalW4) {
    const long i = t * 4;
    const int l = (int)(i / (3 * per));
    long rem = i - (long)l * 3 * per;
    const int which = (int)(rem / per);
    const long e = rem - (long)which * per;
    const float* s = (which == 0) ? Wq : ((which == 1) ? Wk : Wv);
    const float4 v = *(const float4*)&s[(long)l * per + e];
    half4 h = {(f16)v.x, (f16)v.y, (f16)v.z, (f16)v.w};
    *(half4*)&Wo[i] = h;
  }
  if (t < (long)Ln * 3 * Dn) {  // 13824 bias elems
    int l = (int)(t / (3 * Dn));
    int rem = (int)(t % (3 * Dn));
    int which = rem / Dn, c = rem % Dn;
    const float* s = (which == 0) ? bq : ((which == 1) ? bk : bv);
    bo[t] = s[l * Dn + c];
  }
}

__global__ __launch_bounds__(256) void f32_to_f16_k(
    const float* __restrict__ src, f16* __restrict__ dst, long n) {
  long i = ((long)blockIdx.x * 256 + threadIdx.x) * 4;
  if (i < n) {
    float4 v = *(const float4*)&src[i];
    half4 h = {(f16)v.x, (f16)v.y, (f16)v.z, (f16)v.w};
    *(half4*)&dst[i] = h;
  }
}

// ---------------------------------------------------------------------------
// Embedding gather + positional encoding -> fp32 X and fp16 Xh
// ---------------------------------------------------------------------------
__global__ __launch_bounds__(256) void embed_k(
    const int* __restrict__ ids, const float* __restrict__ emb, const float* __restrict__ pe,
    float* __restrict__ Xf, f16* __restrict__ Xh) {
  const int row = blockIdx.x;           // 0..8191
  const int s = row & (Sn - 1);
  const int id = ids[row];
  const size_t eb = (size_t)id * Dn, pb = (size_t)s * Dn, ob = (size_t)row * Dn;
  for (int c = threadIdx.x; c < Dn; c += 256) {
    float v = emb[eb + c] + pe[pb + c];
    Xf[ob + c] = v;
    Xh[ob + c] = (f16)v;
  }
}

// ---------------------------------------------------------------------------
// bt-GEMM: C(M,N) = A(MxK) @ B(NxK)^T + bias, 128x128x32 tile, 4 waves.
// Row stride of A and B is lda (= full K dim); K is the loop extent.
// MODE 1: relu + fp16 out.  MODE 3: fp16 QKV split.
// MODE 4: split-K partial (blockIdx.z selects K-chunk), fp32, NO bias.
// ---------------------------------------------------------------------------
template <int MODE>
__global__ __launch_bounds__(256) void gemm_bt(
    const f16* __restrict__ A, const f16* __restrict__ Bw, const float* __restrict__ bias,
    float* __restrict__ outF, f16* __restrict__ o0, f16* __restrict__ o1, f16* __restrict__ o2,
    int M, int N, int K, int lda) {
  const int m0 = blockIdx.x * 128;
  const int n0 = blockIdx.y * 128;
  const int tid = threadIdx.x;
  const int lane = tid & 63, wave = tid >> 6;
  const int wm = wave & 1, wn = wave >> 1;
  const int l15 = lane & 15, l4 = lane >> 4;

  __shared__ __align__(16) f16 As[128 * 32];  // unpadded: required by glds
  __shared__ __align__(16) f16 Bs[128 * 32];

  const f32x4 z4 = {0.f, 0.f, 0.f, 0.f};
  f32x4 acc[4][4];
#pragma unroll
  for (int i = 0; i < 4; i++)
#pragma unroll
    for (int j = 0; j < 4; j++) acc[i][j] = z4;

  const int sRow = wave * 32 + (lane >> 2);
  const int sCol = (lane & 3) * 8;
  const int kz = (MODE == 4) ? ((int)blockIdx.z * K) : 0;
  const f16* gA = A + (size_t)(m0 + sRow) * lda + kz + sCol;
  const f16* gB = Bw + (size_t)(n0 + sRow) * lda + kz + sCol;
  f16* lA0 = &As[(wave * 32) * 32];
  f16* lA1 = &As[(wave * 32 + 16) * 32];
  f16* lB0 = &Bs[(wave * 32) * 32];
  f16* lB1 = &Bs[(wave * 32 + 16) * 32];
  const size_t rowStep = (size_t)16 * lda;

  const int kr = 8 * l4;
  for (int k0 = 0; k0 < K; k0 += 32) {
    glds16(gA + k0, lA0);
    glds16(gA + k0 + rowStep, lA1);
    glds16(gB + k0, lB0);
    glds16(gB + k0 + rowStep, lB1);
    __syncthreads();  // drains vmcnt -> DMA visible to all waves
    half8 af[4], bfr[4];
#pragma unroll
    for (int i = 0; i < 4; i++) af[i] = *(const half8*)&As[(wm * 64 + i * 16 + l15) * 32 + kr];
#pragma unroll
    for (int j = 0; j < 4; j++) bfr[j] = *(const half8*)&Bs[(wn * 64 + j * 16 + l15) * 32 + kr];
#pragma unroll
    for (int i = 0; i < 4; i++)
#pragma unroll
      for (int j = 0; j < 4; j++)
        acc[i][j] = __builtin_amdgcn_mfma_f32_16x16x32_f16(af[i], bfr[j], acc[i][j], 0, 0, 0);
    __syncthreads();  // all reads done before next iteration's DMA overwrites
  }

  const int colb = n0 + wn * 64;
  const int rowb = m0 + wm * 64;
#pragma unroll
  for (int j = 0; j < 4; j++) {
    const int col = colb + j * 16 + l15;
    const float bb = (MODE == 4) ? 0.f : bias[col];
#pragma unroll
    for (int i = 0; i < 4; i++) {
      const int rb = rowb + i * 16 + l4 * 4;
#pragma unroll
      for (int r = 0; r < 4; r++) {
        float v = acc[i][j][r] + bb;
        const int row = rb + r;
        if (MODE == 1) {
          v = fmaxf(v, 0.f);
          o0[(size_t)row * N + col] = (f16)v;
        } else if (MODE == 3) {
          const int sel = col / 768;          // block-uniform (768 % 128 == 0)
          const int cl = col - sel * 768;
          f16* op = (sel == 0) ? o0 : ((sel == 1) ? o1 : o2);
          op[(size_t)row * 768 + cl] = (f16)v;
        } else if (MODE == 4) {
          outF[((size_t)blockIdx.z * M + row) * N + col] = v;
        } else {
          o0[(size_t)row * N + col] = (f16)v;
        }
      }
    }
  }
}

// ---------------------------------------------------------------------------
// Flash attention: one block = (b,h) x 128 q-rows; 4 waves x 32 rows each.
// 32x32x16 MFMA, swapped QK^T (S^T = K·Q^T): lane owns q-column (q = lane&31),
// partner lane (^32) holds complementary 32 kpos. Softmax fully in-register.
// PV computes O^T = V^T · P^T so per-q state never crosses lanes.
// ---------------------------------------------------------------------------
__global__ __launch_bounds__(256, 3) void attn_k(
    const f16* __restrict__ Qg, const f16* __restrict__ Kg, const f16* __restrict__ Vg,
    float* __restrict__ O) {
  const int bh = blockIdx.x;            // 0..95
  const int q0 = blockIdx.y * 128;
  const int b = bh / Hn, h = bh - b * Hn;
  const size_t base = (size_t)b * (Sn * Dn) + (size_t)h * (Sn * HDn);
  const f16* Qh = Qg + base;
  const f16* Kh = Kg + base;
  const f16* Vh = Vg + base;

  const int tid = threadIdx.x, lane = tid & 63, wave = tid >> 6;
  const int l31 = lane & 31;
  const int hi = lane >> 5;             // 0/1: which half of the 64-kpos tile

  __shared__ __align__(16) f16 Ks[64 * 72];   // (kpos, hd), padded stride 72
  __shared__ __align__(16) f16 Vt[64 * 72];   // (hd, kpos), padded stride 72

  const int qrow = q0 + wave * 32 + l31;
  half8 qf[4];
#pragma unroll
  for (int m = 0; m < 4; m++)
    qf[m] = *(const half8*)&Qh[(size_t)qrow * HDn + 16 * m + 8 * hi];

  f32x16 Oacc0, Oacc1;
#pragma unroll
  for (int i = 0; i < 16; i++) { Oacc0[i] = 0.f; Oacc1[i] = 0.f; }
  float mrow = -1e30f, lrow = 0.f;
  const float csc = 0.18033688011112042f;  // 0.125 * log2(e)

  for (int kt = 0; kt < Sn / 64; ++kt) {
    // stage K tile 64x64 (row-major, conflict-free b128 writes)
#pragma unroll
    for (int cc = 0; cc < 2; cc++) {
      const int c = tid + cc * 256;
      const int row = c >> 3, col = (c & 7) * 8;
      *(int4*)&Ks[row * 72 + col] = *(const int4*)&Kh[(size_t)(kt * 64 + row) * HDn + col];
    }
    // stage V transposed: 8 coalesced col-gathers -> one aligned b128 write
#pragma unroll
    for (int ee = 0; ee < 2; ee++) {
      const int e = tid + ee * 256;
      const int hd = e & 63, kpo = e >> 6;
      f16 tmp[8];
#pragma unroll
      for (int j = 0; j < 8; j++)
        tmp[j] = Vh[(size_t)(kt * 64 + kpo * 8 + j) * HDn + hd];
      *(int4*)&Vt[hd * 72 + kpo * 8] = *(const int4*)tmp;
    }
    __syncthreads();

    // QK^T swapped: S^T (64 kpos x 32 q) as two 32x32 tiles, contraction hd=64
    f32x16 s0, s1;
#pragma unroll
    for (int i = 0; i < 16; i++) { s0[i] = 0.f; s1[i] = 0.f; }
#pragma unroll
    for (int m = 0; m < 4; m++) {
      half8 k0 = *(const half8*)&Ks[l31 * 72 + 16 * m + 8 * hi];
      half8 k1 = *(const half8*)&Ks[(32 + l31) * 72 + 16 * m + 8 * hi];
      s0 = __builtin_amdgcn_mfma_f32_32x32x16_f16(k0, qf[m], s0, 0, 0, 0);
      s1 = __builtin_amdgcn_mfma_f32_32x32x16_f16(k1, qf[m], s1, 0, 0, 0);
    }

    // column max over 64 kpos: in-register tree + one partner exchange
    float t8[8];
#pragma unroll
    for (int i = 0; i < 8; i++)
      t8[i] = fmaxf(fmaxf(s0[i], s0[i + 8]), fmaxf(s1[i], s1[i + 8]));
#pragma unroll
    for (int i = 0; i < 4; i++) t8[i] = fmaxf(t8[i], t8[i + 4]);
    float mx = fmaxf(fmaxf(t8[0], t8[1]), fmaxf(t8[2], t8[3]));
    mx = fmaxf(mx, __shfl_xor(mx, 32));
    const float M = fmaxf(mrow, mx * csc);
    const float alpha = ex2(mrow - M);

    // p = exp2(s*csc - M), in place
#pragma unroll
    for (int i = 0; i < 16; i++) {
      s0[i] = ex2(fmaf(s0[i], csc, -M));
      s1[i] = ex2(fmaf(s1[i], csc, -M));
    }
    float r0 = 0.f, r1 = 0.f, r2 = 0.f, r3 = 0.f;
#pragma unroll
    for (int i = 0; i < 16; i += 4) {
      r0 += s0[i]; r1 += s0[i + 1]; r2 += s0[i + 2]; r3 += s0[i + 3];
      r0 += s1[i]; r1 += s1[i + 1]; r2 += s1[i + 2]; r3 += s1[i + 3];
    }
    float rsum = (r0 + r1) + (r2 + r3);
    rsum += __shfl_xor(rsum, 32);
    lrow = lrow * alpha + rsum;
    mrow = M;
#pragma unroll
    for (int i = 0; i < 16; i++) { Oacc0[i] *= alpha; Oacc1[i] *= alpha; }

    // pack P (f32 -> packed f16 pairs)
    unsigned pA[2][4], pB[2][4];
#pragma unroll
    for (int t = 0; t < 4; t++) {
      pA[0][t] = __builtin_bit_cast(unsigned, __builtin_amdgcn_cvt_pkrtz(s0[4 * t + 0], s0[4 * t + 1]));
      pB[0][t] = __builtin_bit_cast(unsigned, __builtin_amdgcn_cvt_pkrtz(s0[4 * t + 2], s0[4 * t + 3]));
      pA[1][t] = __builtin_bit_cast(unsigned, __builtin_amdgcn_cvt_pkrtz(s1[4 * t + 0], s1[4 * t + 1]));
      pB[1][t] = __builtin_bit_cast(unsigned, __builtin_amdgcn_cvt_pkrtz(s1[4 * t + 2], s1[4 * t + 3]));
    }

    // PV: O^T (64 hd x 32 q) += V^T · P^T, 4 chunks of 16 kpos
#pragma unroll
    for (int c = 0; c < 4; c++) {
      const int g = c >> 1, tt = 2 * (c & 1);
      const unsigned ownA = hi ? pA[g][tt + 1] : pA[g][tt];
      const unsigned ownB = hi ? pB[g][tt + 1] : pB[g][tt];
      const unsigned sndA = hi ? pA[g][tt] : pA[g][tt + 1];
      const unsigned sndB = hi ? pB[g][tt] : pB[g][tt + 1];
      const unsigned rA = (unsigned)__shfl_xor((int)sndA, 32);
      const unsigned rB = (unsigned)__shfl_xor((int)sndB, 32);
      int4 w;
      w.x = (int)(hi ? rA : ownA);
      w.y = (int)(hi ? rB : ownB);
      w.z = (int)(hi ? ownA : rA);
      w.w = (int)(hi ? ownB : rB);
      const half8 pf = __builtin_bit_cast(half8, w);
      const half8 v0 = *(const half8*)&Vt[l31 * 72 + 16 * c + 8 * hi];
      const half8 v1 = *(const half8*)&Vt[(32 + l31) * 72 + 16 * c + 8 * hi];
      Oacc0 = __builtin_amdgcn_mfma_f32_32x32x16_f16(v0, pf, Oacc0, 0, 0, 0);
      Oacc1 = __builtin_amdgcn_mfma_f32_32x32x16_f16(v1, pf, Oacc1, 0, 0, 0);
    }
    __syncthreads();
  }

  // finalize: O[b][s=qrow][h*64 + hd], hd = ht*32 + 8t + 4*hi + e (contiguous 4)
  const float inv = 1.f / lrow;
  float* Orow = O + ((size_t)b * Sn + qrow) * Dn + h * HDn;
#pragma unroll
  for (int t = 0; t < 4; t++) {
    float4 o0, o1;
    o0.x = Oacc0[4 * t + 0] * inv; o0.y = Oacc0[4 * t + 1] * inv;
    o0.z = Oacc0[4 * t + 2] * inv; o0.w = Oacc0[4 * t + 3] * inv;
    o1.x = Oacc1[4 * t + 0] * inv; o1.y = Oacc1[4 * t + 1] * inv;
    o1.z = Oacc1[4 * t + 2] * inv; o1.w = Oacc1[4 * t + 3] * inv;
    *(float4*)&Orow[8 * t + 4 * hi] = o0;
    *(float4*)&Orow[32 + 8 * t + 4 * hi] = o1;
  }
}

// ---------------------------------------------------------------------------
// Residual add + LayerNorm over D=768, one block per row (256 thr x 3 elems).
// ---------------------------------------------------------------------------
__global__ __launch_bounds__(256) void add_ln(
    const float* __restrict__ Xi, const float* __restrict__ Hr,
    const float* __restrict__ g, const float* __restrict__ bt,
    float* __restrict__ Yf, f16* __restrict__ Yh) {
  const int row = blockIdx.x;
  const int tid = threadIdx.x;
  const size_t base = (size_t)row * Dn;
  float v0 = Xi[base + tid] + Hr[base + tid];
  float v1 = Xi[base + tid + 256] + Hr[base + tid + 256];
  float v2 = Xi[base + tid + 512] + Hr[base + tid + 512];

  __shared__ float red[8];
  float s = v0 + v1 + v2;
  for (int off = 32; off; off >>= 1) s += __shfl_down(s, off);
  const int wv = tid >> 6, ln = tid & 63;
  if (ln == 0) red[wv] = s;
  __syncthreads();
  if (tid == 0) red[4] = (red[0] + red[1] + red[2] + red[3]) * (1.f / Dn);
  __syncthreads();
  const float mu = red[4];
  const float d0 = v0 - mu, d1 = v1 - mu, d2 = v2 - mu;
  float vs = d0 * d0 + d1 * d1 + d2 * d2;
  for (int off = 32; off; off >>= 1) vs += __shfl_down(vs, off);
  if (ln == 0) red[wv] = vs;
  __syncthreads();
  if (tid == 0) red[5] = rsqrtf((red[0] + red[1] + red[2] + red[3]) * (1.f / Dn) + 1e-5f);
  __syncthreads();
  const float rs = red[5];
  float y0 = d0 * rs * g[tid] + bt[tid];
  float y1 = d1 * rs * g[tid + 256] + bt[tid + 256];
  float y2 = d2 * rs * g[tid + 512] + bt[tid + 512];
  Yf[base + tid] = y0;        Yh[base + tid] = (f16)y0;
  Yf[base + tid + 256] = y1;  Yh[base + tid + 256] = (f16)y1;
  Yf[base + tid + 512] = y2;  Yh[base + tid + 512] = (f16)y2;
}

// ---------------------------------------------------------------------------
// add_ln_sk2: residual + split-K2 partial sum + bias, then LayerNorm.
// h2 = P0 + P1 + b2;  y = LN(Xi + h2).
// ---------------------------------------------------------------------------
__global__ __launch_bounds__(256) void add_ln_sk2(
    const float* __restrict__ Xi, const float* __restrict__ P,
    const float* __restrict__ b2, const float* __restrict__ g, const float* __restrict__ bt,
    float* __restrict__ Yf, f16* __restrict__ Yh) {
  const int row = blockIdx.x;
  const int tid = threadIdx.x;
  const size_t base = (size_t)row * Dn;
  const size_t cs = (size_t)BS * Dn;
  float v0 = Xi[base + tid]       + P[base + tid]       + P[cs + base + tid]       + b2[tid];
  float v1 = Xi[base + tid + 256] + P[base + tid + 256] + P[cs + base + tid + 256] + b2[tid + 256];
  float v2 = Xi[base + tid + 512] + P[base + tid + 512] + P[cs + base + tid + 512] + b2[tid + 512];

  __shared__ float red[8];
  float s = v0 + v1 + v2;
  for (int off = 32; off; off >>= 1) s += __shfl_down(s, off);
  const int wv = tid >> 6, ln = tid & 63;
  if (ln == 0) red[wv] = s;
  __syncthreads();
  if (tid == 0) red[4] = (red[0] + red[1] + red[2] + red[3]) * (1.f / Dn);
  __syncthreads();
  const float mu = red[4];
  const float d0 = v0 - mu, d1 = v1 - mu, d2 = v2 - mu;
  float vs = d0 * d0 + d1 * d1 + d2 * d2;
  for (int off = 32; off; off >>= 1) vs += __shfl_down(vs, off);
  if (ln == 0) red[wv] = vs;
  __syncthreads();
  if (tid == 0) red[5] = rsqrtf((red[0] + red[1] + red[2] + red[3]) * (1.f / Dn) + 1e-5f);
  __syncthreads();
  const float rs = red[5];
  float y0 = d0 * rs * g[tid] + bt[tid];
  float y1 = d1 * rs * g[tid + 256] + bt[tid + 256];
  float y2 = d2 * rs * g[tid + 512] + bt[tid + 512];
  Yf[base + tid] = y0;        Yh[base + tid] = (f16)y0;
  Yf[base + tid + 256] = y1;  Yh[base + tid + 256] = (f16)y1;
  Yf[base + tid + 512] = y2;  Yh[base + tid + 512] = (f16)y2;
}

// ---------------------------------------------------------------------------
extern "C" void kernel_launch(void* const* d_in, const int* in_sizes, int n_in,
                              void* d_out, int out_size, void* d_ws, size_t ws_size,
                              hipStream_t stream) {
  const int* ids  = (const int*)d_in[0];
  const float* emb = (const float*)d_in[1];
  const float* pe  = (const float*)d_in[2];
  const float* Wq  = (const float*)d_in[3];
  const float* bq  = (const float*)d_in[4];
  const float* Wk  = (const float*)d_in[5];
  const float* bk  = (const float*)d_in[6];
  const float* Wv  = (const float*)d_in[7];
  const float* bv  = (const float*)d_in[8];
  const float* W1  = (const float*)d_in[9];
  const float* b1  = (const float*)d_in[10];
  const float* W2  = (const float*)d_in[11];
  const float* b2  = (const float*)d_in[12];
  const float* g1  = (const float*)d_in[13];
  const float* be1 = (const float*)d_in[14];
  const float* g2  = (const float*)d_in[15];
  const float* be2 = (const float*)d_in[16];
  float* out = (float*)d_out;

  // workspace layout (~292 MB)
  char* w = (char*)d_ws;
  auto alloc = [&](size_t bytes) {
    char* p = w;
    w += (bytes + 255) & ~(size_t)255;
    return p;
  };
  f16* Wqkv  = (f16*)alloc((size_t)Ln * 3 * Dn * Dn * 2);
  float* bqkv = (float*)alloc((size_t)Ln * 3 * Dn * 4);
  f16* W1h   = (f16*)alloc((size_t)Ln * DFn * Dn * 2);
  f16* W2h   = (f16*)alloc((size_t)Ln * Dn * DFn * 2);
  float* Xf  = (float*)alloc((size_t)BS * Dn * 4);
  f16* Xh    = (f16*)alloc((size_t)BS * Dn * 2);
  f16* Qh    = (f16*)alloc((size_t)BS * Dn * 2);
  f16* Kh    = (f16*)alloc((size_t)BS * Dn * 2);
  f16* Vh    = (f16*)alloc((size_t)BS * Dn * 2);
  float* Of  = (float*)alloc((size_t)BS * Dn * 4);
  float* Y1f = (float*)alloc((size_t)BS * Dn * 4);
  f16* Y1h   = (f16*)alloc((size_t)BS * Dn * 2);
  f16* F1h   = (f16*)alloc((size_t)BS * DFn * 2);

  // FFN2 split-K2 partials: 2 x 8192 x 768 fp32 = 50.3 MB, overlaid on the
  // Qh/Kh/Vh/Of region (62.9 MB contiguous, dead after add_ln #1 consumes Of;
  // next use of Qh is next layer's QKV gemm, after add_ln_sk2 has read P).
  float* Pf = (float*)Qh;

  // weight conversion (every call; harness re-poisons ws)
  {
    const long totalW4 = (long)Ln * 3 * Dn * Dn / 4;
    const int gw = (int)((totalW4 + 255) / 256);    // 10368 blocks
    pack_qkv<<<gw, 256, 0, stream>>>(Wq, Wk, Wv, bq, bk, bv, Wqkv, bqkv);
    const long n1 = (long)Ln * DFn * Dn;
    const int gc = (int)(n1 / 4 / 256);             // 13824
    f32_to_f16_k<<<gc, 256, 0, stream>>>(W1, W1h, n1);
    f32_to_f16_k<<<gc, 256, 0, stream>>>(W2, W2h, n1);
  }

  embed_k<<<BS, 256, 0, stream>>>(ids, emb, pe, Xf, Xh);

  for (int l = 0; l < Ln; ++l) {
    // QKV: (8192 x 2304) = Xh @ Wqkv^T, split-written to Qh/Kh/Vh
    gemm_bt<3><<<dim3(BS / 128, (3 * Dn) / 128), 256, 0, stream>>>(
        Xh, Wqkv + (size_t)l * 3 * Dn * Dn, bqkv + l * 3 * Dn,
        nullptr, Qh, Kh, Vh, BS, 3 * Dn, Dn, Dn);

    attn_k<<<dim3(Bn * Hn, Sn / 128), 256, 0, stream>>>(Qh, Kh, Vh, Of);

    add_ln<<<BS, 256, 0, stream>>>(Xf, Of, g1 + l * Dn, be1 + l * Dn, Y1f, Y1h);

    // FFN1: relu(Y1 @ W1^T + b1) -> fp16
    gemm_bt<1><<<dim3(BS / 128, DFn / 128), 256, 0, stream>>>(
        Y1h, W1h + (size_t)l * DFn * Dn, b1 + l * DFn,
        nullptr, F1h, nullptr, nullptr, BS, DFn, Dn, Dn);

    // FFN2: split-K2 -> fp32 partials (768 blocks = 3/CU, was 384 = 1.5/CU)
    gemm_bt<4><<<dim3(BS / 128, Dn / 128, 2), 256, 0, stream>>>(
        F1h, W2h + (size_t)l * Dn * DFn, nullptr,
        Pf, nullptr, nullptr, nullptr, BS, Dn, DFn / 2, DFn);

    float* dstF = (l == Ln - 1) ? out : Xf;
    add_ln_sk2<<<BS, 256, 0, stream>>>(Y1f, Pf, b2 + l * Dn,
                                       g2 + l * Dn, be2 + l * Dn, dstF, Xh);
  }
}

// Round 3
// 1815.549 us; speedup vs baseline: 1.2960x; 1.0611x over previous
//
#include <hip/hip_runtime.h>

// ---------------------------------------------------------------------------
// 6-layer Transformer encoder, MI355X gfx950.
// fp16 MFMA GEMMs + flash attention, fp32 residual/LN chain.
// R7: GEMM K-loop 1-phase -> 2-phase double-buffered LDS (T3 minimum recipe):
//     STAGE(next) || compute(cur), ONE barrier/iter (was 2), load latency
//     hidden under MFMA instead of exposed at a vmcnt(0) drain every K-step.
//     LDS 16 KB -> 32 KB (still 5 blocks/CU). Applies to QKV/FFN1/FFN2.
// R6: FFN2 split-K2 (768 blocks = 3/CU), partials summed in add_ln_sk2.
// R5: attention on mfma_32x32x16 with swapped QK^T, in-register softmax.
// ---------------------------------------------------------------------------

typedef _Float16 f16;
typedef _Float16 half4 __attribute__((ext_vector_type(4)));
typedef _Float16 half8 __attribute__((ext_vector_type(8)));
typedef float f32x4 __attribute__((ext_vector_type(4)));
typedef float f32x16 __attribute__((ext_vector_type(16)));

constexpr int Bn = 8, Sn = 1024, Dn = 768, Hn = 12, HDn = 64, DFn = 3072, Ln = 6;
constexpr int BS = Bn * Sn;  // 8192 rows

__device__ __forceinline__ void glds16(const f16* g, f16* l) {
  __builtin_amdgcn_global_load_lds(
      (const __attribute__((address_space(1))) unsigned int*)g,
      (__attribute__((address_space(3))) unsigned int*)l, 16, 0, 0);
}

__device__ __forceinline__ float ex2(float x) {
#if __has_builtin(__builtin_amdgcn_exp2f)
  return __builtin_amdgcn_exp2f(x);
#else
  return exp2f(x);
#endif
}

// ---------------------------------------------------------------------------
// Weight prep: pack [Wq;Wk;Wv] per layer into (2304 x 768) fp16 + packed bias
// ---------------------------------------------------------------------------
__global__ __launch_bounds__(256) void pack_qkv(
    const float* __restrict__ Wq, const float* __restrict__ Wk, const float* __restrict__ Wv,
    const float* __restrict__ bq, const float* __restrict__ bk, const float* __restrict__ bv,
    f16* __restrict__ Wo, float* __restrict__ bo) {
  const long per = (long)Dn * Dn;  // 589824
  const long t = (long)blockIdx.x * 256 + threadIdx.x;
  const long totalW4 = (long)Ln * 3 * per / 4;  // 2,654,208
  if (t < totalW4) {
    const long i = t * 4;
    const int l = (int)(i / (3 * per));
    long rem = i - (long)l * 3 * per;
    const int which = (int)(rem / per);
    const long e = rem - (long)which * per;
    const float* s = (which == 0) ? Wq : ((which == 1) ? Wk : Wv);
    const float4 v = *(const float4*)&s[(long)l * per + e];
    half4 h = {(f16)v.x, (f16)v.y, (f16)v.z, (f16)v.w};
    *(half4*)&Wo[i] = h;
  }
  if (t < (long)Ln * 3 * Dn) {  // 13824 bias elems
    int l = (int)(t / (3 * Dn));
    int rem = (int)(t % (3 * Dn));
    int which = rem / Dn, c = rem % Dn;
    const float* s = (which == 0) ? bq : ((which == 1) ? bk : bv);
    bo[t] = s[l * Dn + c];
  }
}

__global__ __launch_bounds__(256) void f32_to_f16_k(
    const float* __restrict__ src, f16* __restrict__ dst, long n) {
  long i = ((long)blockIdx.x * 256 + threadIdx.x) * 4;
  if (i < n) {
    float4 v = *(const float4*)&src[i];
    half4 h = {(f16)v.x, (f16)v.y, (f16)v.z, (f16)v.w};
    *(half4*)&dst[i] = h;
  }
}

// ---------------------------------------------------------------------------
// Embedding gather + positional encoding -> fp32 X and fp16 Xh
// ---------------------------------------------------------------------------
__global__ __launch_bounds__(256) void embed_k(
    const int* __restrict__ ids, const float* __restrict__ emb, const float* __restrict__ pe,
    float* __restrict__ Xf, f16* __restrict__ Xh) {
  const int row = blockIdx.x;           // 0..8191
  const int s = row & (Sn - 1);
  const int id = ids[row];
  const size_t eb = (size_t)id * Dn, pb = (size_t)s * Dn, ob = (size_t)row * Dn;
  for (int c = threadIdx.x; c < Dn; c += 256) {
    float v = emb[eb + c] + pe[pb + c];
    Xf[ob + c] = v;
    Xh[ob + c] = (f16)v;
  }
}

// ---------------------------------------------------------------------------
// bt-GEMM: C(M,N) = A(MxK) @ B(NxK)^T + bias, 128x128x32 tile, 4 waves.
// 2-phase double-buffered: stage tile t+1 while computing tile t, one
// barrier per K-step (the __syncthreads vmcnt(0) drain lands after the
// staged loads have had the whole compute phase in flight).
// Row stride of A and B is lda (= full K dim); K is the loop extent.
// MODE 1: relu + fp16 out.  MODE 3: fp16 QKV split.
// MODE 4: split-K partial (blockIdx.z selects K-chunk), fp32, NO bias.
// ---------------------------------------------------------------------------
template <int MODE>
__global__ __launch_bounds__(256) void gemm_bt(
    const f16* __restrict__ A, const f16* __restrict__ Bw, const float* __restrict__ bias,
    float* __restrict__ outF, f16* __restrict__ o0, f16* __restrict__ o1, f16* __restrict__ o2,
    int M, int N, int K, int lda) {
  const int m0 = blockIdx.x * 128;
  const int n0 = blockIdx.y * 128;
  const int tid = threadIdx.x;
  const int lane = tid & 63, wave = tid >> 6;
  const int wm = wave & 1, wn = wave >> 1;
  const int l15 = lane & 15, l4 = lane >> 4;

  constexpr int TILE = 128 * 32;  // elems per buffer
  __shared__ __align__(16) f16 As[2 * TILE];  // unpadded: required by glds
  __shared__ __align__(16) f16 Bs[2 * TILE];

  const f32x4 z4 = {0.f, 0.f, 0.f, 0.f};
  f32x4 acc[4][4];
#pragma unroll
  for (int i = 0; i < 4; i++)
#pragma unroll
    for (int j = 0; j < 4; j++) acc[i][j] = z4;

  // staging geometry: each wave DMAs rows [wave*32, wave*32+32) in 2 instrs;
  // lane L covers row base+L/4, col (L&3)*8  (16 B = 8 f16 per lane)
  const int sRow = wave * 32 + (lane >> 2);
  const int sCol = (lane & 3) * 8;
  const int kz = (MODE == 4) ? ((int)blockIdx.z * K) : 0;
  const f16* gA = A + (size_t)(m0 + sRow) * lda + kz + sCol;
  const f16* gB = Bw + (size_t)(n0 + sRow) * lda + kz + sCol;
  f16* lA = &As[(wave * 32) * 32];
  f16* lB = &Bs[(wave * 32) * 32];
  const size_t rowStep = (size_t)16 * lda;

  auto stage = [&](int buf, int k0) {
    glds16(gA + k0, lA + buf * TILE);
    glds16(gA + k0 + rowStep, lA + buf * TILE + 16 * 32);
    glds16(gB + k0, lB + buf * TILE);
    glds16(gB + k0 + rowStep, lB + buf * TILE + 16 * 32);
  };

  // prologue: fill buffer 0
  stage(0, 0);
  __syncthreads();

  const int kr = 8 * l4;
  int cur = 0;
  for (int k0 = 0; k0 < K; k0 += 32) {
    if (k0 + 32 < K) stage(cur ^ 1, k0 + 32);   // prefetch next tile
    half8 af[4], bfr[4];
#pragma unroll
    for (int i = 0; i < 4; i++)
      af[i] = *(const half8*)&As[cur * TILE + (wm * 64 + i * 16 + l15) * 32 + kr];
#pragma unroll
    for (int j = 0; j < 4; j++)
      bfr[j] = *(const half8*)&Bs[cur * TILE + (wn * 64 + j * 16 + l15) * 32 + kr];
#pragma unroll
    for (int i = 0; i < 4; i++)
#pragma unroll
      for (int j = 0; j < 4; j++)
        acc[i][j] = __builtin_amdgcn_mfma_f32_16x16x32_f16(af[i], bfr[j], acc[i][j], 0, 0, 0);
    __syncthreads();  // drains this iter's reads AND next-tile DMA writes
    cur ^= 1;
  }

  const int colb = n0 + wn * 64;
  const int rowb = m0 + wm * 64;
#pragma unroll
  for (int j = 0; j < 4; j++) {
    const int col = colb + j * 16 + l15;
    const float bb = (MODE == 4) ? 0.f : bias[col];
#pragma unroll
    for (int i = 0; i < 4; i++) {
      const int rb = rowb + i * 16 + l4 * 4;
#pragma unroll
      for (int r = 0; r < 4; r++) {
        float v = acc[i][j][r] + bb;
        const int row = rb + r;
        if (MODE == 1) {
          v = fmaxf(v, 0.f);
          o0[(size_t)row * N + col] = (f16)v;
        } else if (MODE == 3) {
          const int sel = col / 768;          // block-uniform (768 % 128 == 0)
          const int cl = col - sel * 768;
          f16* op = (sel == 0) ? o0 : ((sel == 1) ? o1 : o2);
          op[(size_t)row * 768 + cl] = (f16)v;
        } else if (MODE == 4) {
          outF[((size_t)blockIdx.z * M + row) * N + col] = v;
        } else {
          o0[(size_t)row * N + col] = (f16)v;
        }
      }
    }
  }
}

// ---------------------------------------------------------------------------
// Flash attention: one block = (b,h) x 128 q-rows; 4 waves x 32 rows each.
// 32x32x16 MFMA, swapped QK^T (S^T = K·Q^T): lane owns q-column (q = lane&31),
// partner lane (^32) holds complementary 32 kpos. Softmax fully in-register.
// PV computes O^T = V^T · P^T so per-q state never crosses lanes.
// ---------------------------------------------------------------------------
__global__ __launch_bounds__(256, 3) void attn_k(
    const f16* __restrict__ Qg, const f16* __restrict__ Kg, const f16* __restrict__ Vg,
    float* __restrict__ O) {
  const int bh = blockIdx.x;            // 0..95
  const int q0 = blockIdx.y * 128;
  const int b = bh / Hn, h = bh - b * Hn;
  const size_t base = (size_t)b * (Sn * Dn) + (size_t)h * (Sn * HDn);
  const f16* Qh = Qg + base;
  const f16* Kh = Kg + base;
  const f16* Vh = Vg + base;

  const int tid = threadIdx.x, lane = tid & 63, wave = tid >> 6;
  const int l31 = lane & 31;
  const int hi = lane >> 5;             // 0/1: which half of the 64-kpos tile

  __shared__ __align__(16) f16 Ks[64 * 72];   // (kpos, hd), padded stride 72
  __shared__ __align__(16) f16 Vt[64 * 72];   // (hd, kpos), padded stride 72

  const int qrow = q0 + wave * 32 + l31;
  half8 qf[4];
#pragma unroll
  for (int m = 0; m < 4; m++)
    qf[m] = *(const half8*)&Qh[(size_t)qrow * HDn + 16 * m + 8 * hi];

  f32x16 Oacc0, Oacc1;
#pragma unroll
  for (int i = 0; i < 16; i++) { Oacc0[i] = 0.f; Oacc1[i] = 0.f; }
  float mrow = -1e30f, lrow = 0.f;
  const float csc = 0.18033688011112042f;  // 0.125 * log2(e)

  for (int kt = 0; kt < Sn / 64; ++kt) {
    // stage K tile 64x64 (row-major, conflict-free b128 writes)
#pragma unroll
    for (int cc = 0; cc < 2; cc++) {
      const int c = tid + cc * 256;
      const int row = c >> 3, col = (c & 7) * 8;
      *(int4*)&Ks[row * 72 + col] = *(const int4*)&Kh[(size_t)(kt * 64 + row) * HDn + col];
    }
    // stage V transposed: 8 coalesced col-gathers -> one aligned b128 write
#pragma unroll
    for (int ee = 0; ee < 2; ee++) {
      const int e = tid + ee * 256;
      const int hd = e & 63, kpo = e >> 6;
      f16 tmp[8];
#pragma unroll
      for (int j = 0; j < 8; j++)
        tmp[j] = Vh[(size_t)(kt * 64 + kpo * 8 + j) * HDn + hd];
      *(int4*)&Vt[hd * 72 + kpo * 8] = *(const int4*)tmp;
    }
    __syncthreads();

    // QK^T swapped: S^T (64 kpos x 32 q) as two 32x32 tiles, contraction hd=64
    f32x16 s0, s1;
#pragma unroll
    for (int i = 0; i < 16; i++) { s0[i] = 0.f; s1[i] = 0.f; }
#pragma unroll
    for (int m = 0; m < 4; m++) {
      half8 k0 = *(const half8*)&Ks[l31 * 72 + 16 * m + 8 * hi];
      half8 k1 = *(const half8*)&Ks[(32 + l31) * 72 + 16 * m + 8 * hi];
      s0 = __builtin_amdgcn_mfma_f32_32x32x16_f16(k0, qf[m], s0, 0, 0, 0);
      s1 = __builtin_amdgcn_mfma_f32_32x32x16_f16(k1, qf[m], s1, 0, 0, 0);
    }

    // column max over 64 kpos: in-register tree + one partner exchange
    float t8[8];
#pragma unroll
    for (int i = 0; i < 8; i++)
      t8[i] = fmaxf(fmaxf(s0[i], s0[i + 8]), fmaxf(s1[i], s1[i + 8]));
#pragma unroll
    for (int i = 0; i < 4; i++) t8[i] = fmaxf(t8[i], t8[i + 4]);
    float mx = fmaxf(fmaxf(t8[0], t8[1]), fmaxf(t8[2], t8[3]));
    mx = fmaxf(mx, __shfl_xor(mx, 32));
    const float M = fmaxf(mrow, mx * csc);
    const float alpha = ex2(mrow - M);

    // p = exp2(s*csc - M), in place
#pragma unroll
    for (int i = 0; i < 16; i++) {
      s0[i] = ex2(fmaf(s0[i], csc, -M));
      s1[i] = ex2(fmaf(s1[i], csc, -M));
    }
    float r0 = 0.f, r1 = 0.f, r2 = 0.f, r3 = 0.f;
#pragma unroll
    for (int i = 0; i < 16; i += 4) {
      r0 += s0[i]; r1 += s0[i + 1]; r2 += s0[i + 2]; r3 += s0[i + 3];
      r0 += s1[i]; r1 += s1[i + 1]; r2 += s1[i + 2]; r3 += s1[i + 3];
    }
    float rsum = (r0 + r1) + (r2 + r3);
    rsum += __shfl_xor(rsum, 32);
    lrow = lrow * alpha + rsum;
    mrow = M;
#pragma unroll
    for (int i = 0; i < 16; i++) { Oacc0[i] *= alpha; Oacc1[i] *= alpha; }

    // pack P (f32 -> packed f16 pairs)
    unsigned pA[2][4], pB[2][4];
#pragma unroll
    for (int t = 0; t < 4; t++) {
      pA[0][t] = __builtin_bit_cast(unsigned, __builtin_amdgcn_cvt_pkrtz(s0[4 * t + 0], s0[4 * t + 1]));
      pB[0][t] = __builtin_bit_cast(unsigned, __builtin_amdgcn_cvt_pkrtz(s0[4 * t + 2], s0[4 * t + 3]));
      pA[1][t] = __builtin_bit_cast(unsigned, __builtin_amdgcn_cvt_pkrtz(s1[4 * t + 0], s1[4 * t + 1]));
      pB[1][t] = __builtin_bit_cast(unsigned, __builtin_amdgcn_cvt_pkrtz(s1[4 * t + 2], s1[4 * t + 3]));
    }

    // PV: O^T (64 hd x 32 q) += V^T · P^T, 4 chunks of 16 kpos
#pragma unroll
    for (int c = 0; c < 4; c++) {
      const int g = c >> 1, tt = 2 * (c & 1);
      const unsigned ownA = hi ? pA[g][tt + 1] : pA[g][tt];
      const unsigned ownB = hi ? pB[g][tt + 1] : pB[g][tt];
      const unsigned sndA = hi ? pA[g][tt] : pA[g][tt + 1];
      const unsigned sndB = hi ? pB[g][tt] : pB[g][tt + 1];
      const unsigned rA = (unsigned)__shfl_xor((int)sndA, 32);
      const unsigned rB = (unsigned)__shfl_xor((int)sndB, 32);
      int4 w;
      w.x = (int)(hi ? rA : ownA);
      w.y = (int)(hi ? rB : ownB);
      w.z = (int)(hi ? ownA : rA);
      w.w = (int)(hi ? ownB : rB);
      const half8 pf = __builtin_bit_cast(half8, w);
      const half8 v0 = *(const half8*)&Vt[l31 * 72 + 16 * c + 8 * hi];
      const half8 v1 = *(const half8*)&Vt[(32 + l31) * 72 + 16 * c + 8 * hi];
      Oacc0 = __builtin_amdgcn_mfma_f32_32x32x16_f16(v0, pf, Oacc0, 0, 0, 0);
      Oacc1 = __builtin_amdgcn_mfma_f32_32x32x16_f16(v1, pf, Oacc1, 0, 0, 0);
    }
    __syncthreads();
  }

  // finalize: O[b][s=qrow][h*64 + hd], hd = ht*32 + 8t + 4*hi + e (contiguous 4)
  const float inv = 1.f / lrow;
  float* Orow = O + ((size_t)b * Sn + qrow) * Dn + h * HDn;
#pragma unroll
  for (int t = 0; t < 4; t++) {
    float4 o0, o1;
    o0.x = Oacc0[4 * t + 0] * inv; o0.y = Oacc0[4 * t + 1] * inv;
    o0.z = Oacc0[4 * t + 2] * inv; o0.w = Oacc0[4 * t + 3] * inv;
    o1.x = Oacc1[4 * t + 0] * inv; o1.y = Oacc1[4 * t + 1] * inv;
    o1.z = Oacc1[4 * t + 2] * inv; o1.w = Oacc1[4 * t + 3] * inv;
    *(float4*)&Orow[8 * t + 4 * hi] = o0;
    *(float4*)&Orow[32 + 8 * t + 4 * hi] = o1;
  }
}

// ---------------------------------------------------------------------------
// Residual add + LayerNorm over D=768, one block per row (256 thr x 3 elems).
// ---------------------------------------------------------------------------
__global__ __launch_bounds__(256) void add_ln(
    const float* __restrict__ Xi, const float* __restrict__ Hr,
    const float* __restrict__ g, const float* __restrict__ bt,
    float* __restrict__ Yf, f16* __restrict__ Yh) {
  const int row = blockIdx.x;
  const int tid = threadIdx.x;
  const size_t base = (size_t)row * Dn;
  float v0 = Xi[base + tid] + Hr[base + tid];
  float v1 = Xi[base + tid + 256] + Hr[base + tid + 256];
  float v2 = Xi[base + tid + 512] + Hr[base + tid + 512];

  __shared__ float red[8];
  float s = v0 + v1 + v2;
  for (int off = 32; off; off >>= 1) s += __shfl_down(s, off);
  const int wv = tid >> 6, ln = tid & 63;
  if (ln == 0) red[wv] = s;
  __syncthreads();
  if (tid == 0) red[4] = (red[0] + red[1] + red[2] + red[3]) * (1.f / Dn);
  __syncthreads();
  const float mu = red[4];
  const float d0 = v0 - mu, d1 = v1 - mu, d2 = v2 - mu;
  float vs = d0 * d0 + d1 * d1 + d2 * d2;
  for (int off = 32; off; off >>= 1) vs += __shfl_down(vs, off);
  if (ln == 0) red[wv] = vs;
  __syncthreads();
  if (tid == 0) red[5] = rsqrtf((red[0] + red[1] + red[2] + red[3]) * (1.f / Dn) + 1e-5f);
  __syncthreads();
  const float rs = red[5];
  float y0 = d0 * rs * g[tid] + bt[tid];
  float y1 = d1 * rs * g[tid + 256] + bt[tid + 256];
  float y2 = d2 * rs * g[tid + 512] + bt[tid + 512];
  Yf[base + tid] = y0;        Yh[base + tid] = (f16)y0;
  Yf[base + tid + 256] = y1;  Yh[base + tid + 256] = (f16)y1;
  Yf[base + tid + 512] = y2;  Yh[base + tid + 512] = (f16)y2;
}

// ---------------------------------------------------------------------------
// add_ln_sk2: residual + split-K2 partial sum + bias, then LayerNorm.
// h2 = P0 + P1 + b2;  y = LN(Xi + h2).
// ---------------------------------------------------------------------------
__global__ __launch_bounds__(256) void add_ln_sk2(
    const float* __restrict__ Xi, const float* __restrict__ P,
    const float* __restrict__ b2, const float* __restrict__ g, const float* __restrict__ bt,
    float* __restrict__ Yf, f16* __restrict__ Yh) {
  const int row = blockIdx.x;
  const int tid = threadIdx.x;
  const size_t base = (size_t)row * Dn;
  const size_t cs = (size_t)BS * Dn;
  float v0 = Xi[base + tid]       + P[base + tid]       + P[cs + base + tid]       + b2[tid];
  float v1 = Xi[base + tid + 256] + P[base + tid + 256] + P[cs + base + tid + 256] + b2[tid + 256];
  float v2 = Xi[base + tid + 512] + P[base + tid + 512] + P[cs + base + tid + 512] + b2[tid + 512];

  __shared__ float red[8];
  float s = v0 + v1 + v2;
  for (int off = 32; off; off >>= 1) s += __shfl_down(s, off);
  const int wv = tid >> 6, ln = tid & 63;
  if (ln == 0) red[wv] = s;
  __syncthreads();
  if (tid == 0) red[4] = (red[0] + red[1] + red[2] + red[3]) * (1.f / Dn);
  __syncthreads();
  const float mu = red[4];
  const float d0 = v0 - mu, d1 = v1 - mu, d2 = v2 - mu;
  float vs = d0 * d0 + d1 * d1 + d2 * d2;
  for (int off = 32; off; off >>= 1) vs += __shfl_down(vs, off);
  if (ln == 0) red[wv] = vs;
  __syncthreads();
  if (tid == 0) red[5] = rsqrtf((red[0] + red[1] + red[2] + red[3]) * (1.f / Dn) + 1e-5f);
  __syncthreads();
  const float rs = red[5];
  float y0 = d0 * rs * g[tid] + bt[tid];
  float y1 = d1 * rs * g[tid + 256] + bt[tid + 256];
  float y2 = d2 * rs * g[tid + 512] + bt[tid + 512];
  Yf[base + tid] = y0;        Yh[base + tid] = (f16)y0;
  Yf[base + tid + 256] = y1;  Yh[base + tid + 256] = (f16)y1;
  Yf[base + tid + 512] = y2;  Yh[base + tid + 512] = (f16)y2;
}

// ---------------------------------------------------------------------------
extern "C" void kernel_launch(void* const* d_in, const int* in_sizes, int n_in,
                              void* d_out, int out_size, void* d_ws, size_t ws_size,
                              hipStream_t stream) {
  const int* ids  = (const int*)d_in[0];
  const float* emb = (const float*)d_in[1];
  const float* pe  = (const float*)d_in[2];
  const float* Wq  = (const float*)d_in[3];
  const float* bq  = (const float*)d_in[4];
  const float* Wk  = (const float*)d_in[5];
  const float* bk  = (const float*)d_in[6];
  const float* Wv  = (const float*)d_in[7];
  const float* bv  = (const float*)d_in[8];
  const float* W1  = (const float*)d_in[9];
  const float* b1  = (const float*)d_in[10];
  const float* W2  = (const float*)d_in[11];
  const float* b2  = (const float*)d_in[12];
  const float* g1  = (const float*)d_in[13];
  const float* be1 = (const float*)d_in[14];
  const float* g2  = (const float*)d_in[15];
  const float* be2 = (const float*)d_in[16];
  float* out = (float*)d_out;

  // workspace layout (~292 MB)
  char* w = (char*)d_ws;
  auto alloc = [&](size_t bytes) {
    char* p = w;
    w += (bytes + 255) & ~(size_t)255;
    return p;
  };
  f16* Wqkv  = (f16*)alloc((size_t)Ln * 3 * Dn * Dn * 2);
  float* bqkv = (float*)alloc((size_t)Ln * 3 * Dn * 4);
  f16* W1h   = (f16*)alloc((size_t)Ln * DFn * Dn * 2);
  f16* W2h   = (f16*)alloc((size_t)Ln * Dn * DFn * 2);
  float* Xf  = (float*)alloc((size_t)BS * Dn * 4);
  f16* Xh    = (f16*)alloc((size_t)BS * Dn * 2);
  f16* Qh    = (f16*)alloc((size_t)BS * Dn * 2);
  f16* Kh    = (f16*)alloc((size_t)BS * Dn * 2);
  f16* Vh    = (f16*)alloc((size_t)BS * Dn * 2);
  float* Of  = (float*)alloc((size_t)BS * Dn * 4);
  float* Y1f = (float*)alloc((size_t)BS * Dn * 4);
  f16* Y1h   = (f16*)alloc((size_t)BS * Dn * 2);
  f16* F1h   = (f16*)alloc((size_t)BS * DFn * 2);

  // FFN2 split-K2 partials: 2 x 8192 x 768 fp32 = 50.3 MB, overlaid on the
  // Qh/Kh/Vh/Of region (62.9 MB contiguous, dead after add_ln #1 consumes Of)
  float* Pf = (float*)Qh;

  // weight conversion (every call; harness re-poisons ws)
  {
    const long totalW4 = (long)Ln * 3 * Dn * Dn / 4;
    const int gw = (int)((totalW4 + 255) / 256);    // 10368 blocks
    pack_qkv<<<gw, 256, 0, stream>>>(Wq, Wk, Wv, bq, bk, bv, Wqkv, bqkv);
    const long n1 = (long)Ln * DFn * Dn;
    const int gc = (int)(n1 / 4 / 256);             // 13824
    f32_to_f16_k<<<gc, 256, 0, stream>>>(W1, W1h, n1);
    f32_to_f16_k<<<gc, 256, 0, stream>>>(W2, W2h, n1);
  }

  embed_k<<<BS, 256, 0, stream>>>(ids, emb, pe, Xf, Xh);

  for (int l = 0; l < Ln; ++l) {
    // QKV: (8192 x 2304) = Xh @ Wqkv^T, split-written to Qh/Kh/Vh
    gemm_bt<3><<<dim3(BS / 128, (3 * Dn) / 128), 256, 0, stream>>>(
        Xh, Wqkv + (size_t)l * 3 * Dn * Dn, bqkv + l * 3 * Dn,
        nullptr, Qh, Kh, Vh, BS, 3 * Dn, Dn, Dn);

    attn_k<<<dim3(Bn * Hn, Sn / 128), 256, 0, stream>>>(Qh, Kh, Vh, Of);

    add_ln<<<BS, 256, 0, stream>>>(Xf, Of, g1 + l * Dn, be1 + l * Dn, Y1f, Y1h);

    // FFN1: relu(Y1 @ W1^T + b1) -> fp16
    gemm_bt<1><<<dim3(BS / 128, DFn / 128), 256, 0, stream>>>(
        Y1h, W1h + (size_t)l * DFn * Dn, b1 + l * DFn,
        nullptr, F1h, nullptr, nullptr, BS, DFn, Dn, Dn);

    // FFN2: split-K2 -> fp32 partials (768 blocks = 3/CU)
    gemm_bt<4><<<dim3(BS / 128, Dn / 128, 2), 256, 0, stream>>>(
        F1h, W2h + (size_t)l * Dn * DFn, nullptr,
        Pf, nullptr, nullptr, nullptr, BS, Dn, DFn / 2, DFn);

    float* dstF = (l == Ln - 1) ? out : Xf;
    add_ln_sk2<<<BS, 256, 0, stream>>>(Y1f, Pf, b2 + l * Dn,
                                       g2 + l * Dn, be2 + l * Dn, dstF, Xh);
  }
}